// Round 11
// baseline (418.999 us; speedup 1.0000x reference)
//
#include <hip/hip_runtime.h>
#include <hip/hip_bf16.h>

// ActLayer: out[b,o] = sum_{i,f} norm(sin(w_f x[b,i] + p_f)) * beta[f,o] * lamb[i,o] + bias[o]
//
// Round-13: eliminate ALL sin duplication (R10 halved it; this removes the rest).
//   BM=16 x BN=512, grid 512 (= 512 m-blocks), TB=256 = 4 waves = 4 n-groups
//   of 128 cols; per-wave MFMA tile 16x128 (identical to the verified R10 wave).
//   Per f-step the block computes 16x64 sins ONCE (4/thread) into double-
//   buffered A_sh[2][2][16][72] (R10's proven dbuf + 1-barrier-per-f-pair
//   cadence). Total sins = B*I*F exactly (was 2x that in R10, 4x in R8).
//   beta is NOT staged in LDS (would be 64KB at BN=512): loaded from global
//   (L2-resident, 1MB) into registers one f-pair ahead (R8's proven prefetch
//   pattern), scaled by r_f in-register (fp32 - more accurate than bf16 brP).
//   Lambda staged in two 256-col chunks per i-tile through L_sh[256][72]
//   (R10's map, one col per thread).
// LDS ~49KB -> 2 blocks/CU, 8 waves/CU (same TLP as R10).
// Proven pieces verbatim: v_perm bf16 pack, rintf range reduction, dbuf
// cadence, MFMA chains, C/D epilogue mapping.

#define TB 256

typedef __attribute__((ext_vector_type(8))) short short8;
typedef __attribute__((ext_vector_type(4))) float floatx4;
typedef __attribute__((ext_vector_type(2))) unsigned int uintx2;
typedef __attribute__((ext_vector_type(4))) unsigned int uintx4;

// pack two fp32 -> two bf16 (round-half-up): two v_add + one v_perm_b32.
__device__ __forceinline__ unsigned pk_bf16(float a, float b) {
    union { float f; unsigned u; } ca, cb;
    ca.f = a; cb.f = b;
    unsigned ua = ca.u + 0x8000u;
    unsigned ub = cb.u + 0x8000u;
    return __builtin_amdgcn_perm(ub, ua, 0x07060302u);
}

// 4 bf16 sin values as 8B packed: sin(2*pi*(x*wfr + pfr)); rndne reduction.
__device__ __forceinline__ uintx2 sin_pack4(const float xv[4], float wfr, float pfr) {
    float s[4];
    #pragma unroll
    for (int j = 0; j < 4; ++j) {
        float tt = fmaf(xv[j], wfr, pfr);
        float u = tt - __builtin_rintf(tt);
        s[j] = __builtin_amdgcn_sinf(u);
    }
    uintx2 r;
    r.x = pk_bf16(s[0], s[1]);
    r.y = pk_bf16(s[2], s[3]);
    return r;
}

__global__ __launch_bounds__(TB, 2)
void actlayer_kernel(const float* __restrict__ x,
                     const float* __restrict__ freqs,
                     const float* __restrict__ phases,
                     const float* __restrict__ beta,
                     const float* __restrict__ lamb,
                     const float* __restrict__ bias,
                     float* __restrict__ out)
{
    constexpr int I = 512, F = 64, O = 512;
    const int t  = threadIdx.x;
    const int m0 = blockIdx.x * 16;

    __shared__ __align__(16) unsigned short A_sh[2][2][16][72]; // sin tiles, dbuf, 9216B
    __shared__ __align__(16) unsigned short L_sh[256][72];      // lambda chunk, 36864B
    __shared__ float wrev_sh[F], prev_sh[F], r_sh[F], m_sh[F];
    __shared__ float c_sh[512];

    // ---- prologue: per-f normalization constants (verbatim) ----
    if (t < F) {
        float wq = freqs[t];
        float ph = phases[t];
        float e1 = expf(-0.5f * wq * wq);
        float mean = e1 * sinf(ph);
        float e2 = expf(-2.0f * wq * wq);
        float var = 0.5f - 0.5f * e2 * cosf(2.0f * ph) - mean * mean;
        float r = 1.0f / sqrtf(1e-3f + var);
        wrev_sh[t] = wq * 0.15915494309189535f;
        prev_sh[t] = ph * 0.15915494309189535f;
        r_sh[t] = r;
        m_sh[t] = mean;
    }
    __syncthreads();
    // c_sh[col] = bias - (sum_f beta*r*mean) * (sum_i lamb[i][col]); 2 cols/thread
    #pragma unroll
    for (int j = 0; j < 2; ++j) {
        int col = t + 256 * j;
        float sb = 0.f;
        #pragma unroll 8
        for (int f = 0; f < F; ++f) sb += beta[f * O + col] * (r_sh[f] * m_sh[f]);
        float sl = 0.f;
        #pragma unroll 8
        for (int i = 0; i < I; ++i) sl += lamb[(size_t)i * O + col];
        c_sh[col] = bias[col] - sb * sl;
    }

    // ---- geometry ----
    const int lane = t & 63;
    const int ng   = t >> 6;          // wave = n-group 0..3 (cols ng*128..+127)
    const int l15  = lane & 15;
    const int quad = lane >> 4;
    const int r0s  = t >> 4;          // A staging row 0..15
    const int kqs  = t & 15;          // A staging k-quad (k = kqs*4..+3)

    floatx4 oacc[8];
    #pragma unroll
    for (int nt = 0; nt < 8; ++nt) oacc[nt] = (floatx4){0.f, 0.f, 0.f, 0.f};
    const floatx4 zero4 = (floatx4){0.f, 0.f, 0.f, 0.f};

    const float* bp = beta + ng * 128 + l15;   // per-lane beta base (col part)

    #pragma unroll 1
    for (int it = 0; it < 8; ++it) {
        const int i0 = it * 64;
        // x -> regs for sin staging: x[m0+r0s][i0 + kqs*4 .. +3]
        float xs[4];
        {
            float4 xv = *(const float4*)(x + (size_t)(m0 + r0s) * I + i0 + kqs * 4);
            xs[0] = xv.x; xs[1] = xv.y; xs[2] = xv.z; xs[3] = xv.w;
        }
        // ---- lambda chunk 0 (cols 0..255) -> L_sh; thread t stages col t ----
        {
            const float* lp = lamb + (size_t)i0 * O + t;
            #pragma unroll
            for (int h = 0; h < 2; ++h) {
                float v[32];
                #pragma unroll
                for (int k = 0; k < 32; ++k) v[k] = lp[(size_t)(h * 32 + k) * O];
                #pragma unroll
                for (int rr = 0; rr < 4; ++rr) {
                    uintx4 w4;
                    w4.x = pk_bf16(v[rr*8+0], v[rr*8+1]);
                    w4.y = pk_bf16(v[rr*8+2], v[rr*8+3]);
                    w4.z = pk_bf16(v[rr*8+4], v[rr*8+5]);
                    w4.w = pk_bf16(v[rr*8+6], v[rr*8+7]);
                    *(uintx4*)&L_sh[t][h * 32 + rr * 8] = w4;
                }
            }
        }
        // sins for f=0,1 -> A_sh[0] (both buffers idle: prev f-loop's last barrier passed)
        *(uintx2*)&A_sh[0][0][r0s][kqs * 4] = sin_pack4(xs, wrev_sh[0], prev_sh[0]);
        *(uintx2*)&A_sh[0][1][r0s][kqs * 4] = sin_pack4(xs, wrev_sh[1], prev_sh[1]);
        __syncthreads();   // chunk 0 + A_sh[0] visible
        short8 lf[2][8];
        if (ng < 2) {
            #pragma unroll
            for (int kk = 0; kk < 2; ++kk)
                #pragma unroll
                for (int nt = 0; nt < 8; ++nt)
                    lf[kk][nt] = *(const short8*)&L_sh[ng*128 + nt*16 + l15][kk*32 + quad*8];
        }
        __syncthreads();   // chunk-0 reads done
        // ---- lambda chunk 1 (cols 256..511) -> L_sh ----
        {
            const float* lp = lamb + (size_t)i0 * O + 256 + t;
            #pragma unroll
            for (int h = 0; h < 2; ++h) {
                float v[32];
                #pragma unroll
                for (int k = 0; k < 32; ++k) v[k] = lp[(size_t)(h * 32 + k) * O];
                #pragma unroll
                for (int rr = 0; rr < 4; ++rr) {
                    uintx4 w4;
                    w4.x = pk_bf16(v[rr*8+0], v[rr*8+1]);
                    w4.y = pk_bf16(v[rr*8+2], v[rr*8+3]);
                    w4.z = pk_bf16(v[rr*8+4], v[rr*8+5]);
                    w4.w = pk_bf16(v[rr*8+6], v[rr*8+7]);
                    *(uintx4*)&L_sh[t][h * 32 + rr * 8] = w4;
                }
            }
        }
        __syncthreads();   // chunk 1 visible
        if (ng >= 2) {
            #pragma unroll
            for (int kk = 0; kk < 2; ++kk)
                #pragma unroll
                for (int nt = 0; nt < 8; ++nt)
                    lf[kk][nt] = *(const short8*)&L_sh[(ng-2)*128 + nt*16 + l15][kk*32 + quad*8];
        }

        // beta prefetch for f=0,1 (global, L2-resident)
        float bA[8], bB[8];
        #pragma unroll
        for (int nt = 0; nt < 8; ++nt) {
            bA[nt] = bp[0 * O + nt * 16];
            bB[nt] = bp[1 * O + nt * 16];
        }
        float rA = r_sh[0], rB = r_sh[1];

        // ---- f-loop: 2 f per iteration, dbuf A_sh, ONE barrier per pair ----
        int cur = 0;
        #pragma unroll 1
        for (int f = 0; f < F; f += 2) {
            // A fragments for f, f+1 (shared sin tile)
            short8 afA0 = *(const short8*)&A_sh[cur][0][l15][quad * 8];
            short8 afA1 = *(const short8*)&A_sh[cur][0][l15][32 + quad * 8];
            short8 afB0 = *(const short8*)&A_sh[cur][1][l15][quad * 8];
            short8 afB1 = *(const short8*)&A_sh[cur][1][l15][32 + quad * 8];
            // scale beta (consumes bA/bB -> they become free for prefetch)
            float brA[8], brB[8];
            #pragma unroll
            for (int q = 0; q < 8; ++q) { brA[q] = bA[q] * rA; brB[q] = bB[q] * rB; }
            const bool more = (f + 2 < F);
            if (more) {
                // prefetch beta f+2,f+3 into the now-dead bA/bB (hidden under MFMA)
                #pragma unroll
                for (int nt = 0; nt < 8; ++nt) {
                    bA[nt] = bp[(f + 2) * O + nt * 16];
                    bB[nt] = bp[(f + 3) * O + nt * 16];
                }
                rA = r_sh[f + 2]; rB = r_sh[f + 3];
                // sins for f+2 -> other buffer, dovetailed before MFMA chain A
                *(uintx2*)&A_sh[cur ^ 1][0][r0s][kqs * 4] =
                    sin_pack4(xs, wrev_sh[f + 2], prev_sh[f + 2]);
            }
            // MFMA chain A
            #pragma unroll
            for (int nt = 0; nt < 8; ++nt) {
                floatx4 s = __builtin_amdgcn_mfma_f32_16x16x32_bf16(
                    afA0, lf[0][nt], zero4, 0, 0, 0);
                s = __builtin_amdgcn_mfma_f32_16x16x32_bf16(
                    afA1, lf[1][nt], s, 0, 0, 0);
                oacc[nt] += brA[nt] * s;
            }
            if (more) {
                // sins for f+3, dovetailed before MFMA chain B
                *(uintx2*)&A_sh[cur ^ 1][1][r0s][kqs * 4] =
                    sin_pack4(xs, wrev_sh[f + 3], prev_sh[f + 3]);
            }
            // MFMA chain B
            #pragma unroll
            for (int nt = 0; nt < 8; ++nt) {
                floatx4 s = __builtin_amdgcn_mfma_f32_16x16x32_bf16(
                    afB0, lf[0][nt], zero4, 0, 0, 0);
                s = __builtin_amdgcn_mfma_f32_16x16x32_bf16(
                    afB1, lf[1][nt], s, 0, 0, 0);
                oacc[nt] += brB[nt] * s;
            }
            __syncthreads();
            cur ^= 1;
        }
    }

    // ---- epilogue: add per-column constant, store fp32 ----
    #pragma unroll
    for (int nt = 0; nt < 8; ++nt) {
        int gn = ng * 128 + nt * 16 + l15;
        float cv = c_sh[gn];
        int gm = m0 + quad * 4;
        #pragma unroll
        for (int rg = 0; rg < 4; ++rg) {
            out[(size_t)(gm + rg) * O + gn] = oacc[nt][rg] + cv;
        }
    }
}

extern "C" void kernel_launch(void* const* d_in, const int* in_sizes, int n_in,
                              void* d_out, int out_size, void* d_ws, size_t ws_size,
                              hipStream_t stream) {
    const float* x      = (const float*)d_in[0];
    const float* freqs  = (const float*)d_in[1];
    const float* phases = (const float*)d_in[2];
    const float* beta   = (const float*)d_in[3];
    const float* lamb   = (const float*)d_in[4];
    const float* bias   = (const float*)d_in[5];
    float* out = (float*)d_out;

    dim3 grid(512);   // 8192/16 m-blocks, BN=512 covers all cols
    dim3 block(TB);
    hipLaunchKernelGGL(actlayer_kernel, grid, block, 0, stream,
                       x, freqs, phases, beta, lamb, bias, out);
}

// Round 12
// 410.189 us; speedup vs baseline: 1.0215x; 1.0215x over previous
//
#include <hip/hip_runtime.h>
#include <hip/hip_bf16.h>

// ActLayer: out[b,o] = sum_{i,f} norm(sin(w_f x[b,i] + p_f)) * beta[f,o] * lamb[i,o] + bias[o]
//
// Round-14: R10 (390us champion) with DOUBLE the TLP and identical work totals.
//   Same block tile BM=32 x BN=256, same grid 512, same A_sh sin-sharing,
//   same L_scr two-chunk lambda staging, same dbuf 1-barrier-per-f-pair
//   cadence -- but TB=512 (8 waves, 2m x 4n), per-wave tile 16x64:
//   4096 waves total = 16 waves/CU = 4 waves/SIMD (was 2). Per-wave regs
//   drop (oacc[4], lf[2][4]).
//   brP moved out of LDS: beta loaded from global (L2-resident) into
//   registers one f-pair ahead (R13-proven pattern), scaled by r_f in fp32.
//   LDS 38.9KB -> both resident blocks fit with slack.
// Proven pieces verbatim: v_perm bf16 pack, rintf range reduction, sin_pack4,
// A_sh layout/cadence, lambda chunk maps, MFMA chains, epilogue mapping.

#define TB 512

typedef __attribute__((ext_vector_type(8))) short short8;
typedef __attribute__((ext_vector_type(4))) float floatx4;
typedef __attribute__((ext_vector_type(2))) unsigned int uintx2;
typedef __attribute__((ext_vector_type(4))) unsigned int uintx4;

// pack two fp32 -> two bf16 (round-half-up): two v_add + one v_perm_b32.
__device__ __forceinline__ unsigned pk_bf16(float a, float b) {
    union { float f; unsigned u; } ca, cb;
    ca.f = a; cb.f = b;
    unsigned ua = ca.u + 0x8000u;
    unsigned ub = cb.u + 0x8000u;
    return __builtin_amdgcn_perm(ub, ua, 0x07060302u);
}

// 4 bf16 sin values as 8B packed: sin(2*pi*(x*wfr + pfr)); rndne reduction.
__device__ __forceinline__ uintx2 sin_pack4(const float xv[4], float wfr, float pfr) {
    float s[4];
    #pragma unroll
    for (int j = 0; j < 4; ++j) {
        float tt = fmaf(xv[j], wfr, pfr);
        float u = tt - __builtin_rintf(tt);
        s[j] = __builtin_amdgcn_sinf(u);
    }
    uintx2 r;
    r.x = pk_bf16(s[0], s[1]);
    r.y = pk_bf16(s[2], s[3]);
    return r;
}

__global__ __launch_bounds__(TB, 4)   // 4 waves/SIMD -> 2 blocks/CU resident
void actlayer_kernel(const float* __restrict__ x,
                     const float* __restrict__ freqs,
                     const float* __restrict__ phases,
                     const float* __restrict__ beta,
                     const float* __restrict__ lamb,
                     const float* __restrict__ bias,
                     float* __restrict__ out)
{
    constexpr int I = 512, F = 64, O = 512;
    const int t  = threadIdx.x;
    const int bx = blockIdx.x;
    const int bn = bx & 1;            // 0..1
    const int bm = bx >> 1;           // 0..255
    const int n0 = bn * 256;
    const int m0 = bm * 32;

    __shared__ __align__(16) unsigned short A_sh[2][2][32][72]; // sin tiles, dbuf, 18432B
    __shared__ __align__(16) unsigned short L_scr[128][72];     // lambda chunk, 18432B
    __shared__ float wrev_sh[F], prev_sh[F], r_sh[F], m_sh[F];
    __shared__ float c_sh[256];

    // ---- prologue: per-f normalization constants (verbatim) ----
    if (t < F) {
        float wq = freqs[t];
        float ph = phases[t];
        float e1 = expf(-0.5f * wq * wq);
        float mean = e1 * sinf(ph);
        float e2 = expf(-2.0f * wq * wq);
        float var = 0.5f - 0.5f * e2 * cosf(2.0f * ph) - mean * mean;
        float r = 1.0f / sqrtf(1e-3f + var);
        wrev_sh[t] = wq * 0.15915494309189535f;
        prev_sh[t] = ph * 0.15915494309189535f;
        r_sh[t] = r;
        m_sh[t] = mean;
    }
    __syncthreads();
    // c_sh[n] = bias - (sum_f beta*r*mean) * (sum_i lamb[i][n]); col n0+t (t<256)
    if (t < 256) {
        int col = n0 + t;
        float sb = 0.f;
        #pragma unroll 8
        for (int f = 0; f < F; ++f) sb += beta[f * O + col] * (r_sh[f] * m_sh[f]);
        float sl = 0.f;
        #pragma unroll 8
        for (int i = 0; i < I; ++i) sl += lamb[(size_t)i * O + col];
        c_sh[t] = bias[col] - sb * sl;
    }

    // ---- wave geometry: 8 waves = 2 m-groups x 4 n-groups; tile 16 x 64 ----
    const int lane = t & 63;
    const int wid  = t >> 6;
    const int mg   = wid >> 2;        // 0..1
    const int ngw  = wid & 3;         // 0..3 (cols n0 + ngw*64 .. +63)
    const int l15  = lane & 15;
    const int quad = lane >> 4;
    // staging maps
    const int r0s = t >> 4;           // A staging row 0..31
    const int kqs = t & 15;           // A staging k-quad (k = kqs*4..+3)
    const int cL  = t & 127;          // L staging col within chunk
    const int khL = t >> 7;           // L staging k-quarter 0..3 (16 k each)

    floatx4 oacc[4];
    #pragma unroll
    for (int nt = 0; nt < 4; ++nt) oacc[nt] = (floatx4){0.f, 0.f, 0.f, 0.f};
    const floatx4 zero4 = (floatx4){0.f, 0.f, 0.f, 0.f};

    const float* bp = beta + n0 + ngw * 64 + l15;   // per-lane beta column base

    #pragma unroll 1
    for (int it = 0; it < 8; ++it) {
        const int i0 = it * 64;
        // ---- lambda chunk 0 (cols n0..n0+127) -> L_scr ----
        {
            const float* lp = lamb + (size_t)(i0 + khL * 16) * O + n0 + cL;
            float v[16];
            #pragma unroll
            for (int k = 0; k < 16; ++k) v[k] = lp[(size_t)k * O];
            #pragma unroll
            for (int rr = 0; rr < 2; ++rr) {
                uintx4 w4;
                w4.x = pk_bf16(v[rr*8+0], v[rr*8+1]);
                w4.y = pk_bf16(v[rr*8+2], v[rr*8+3]);
                w4.z = pk_bf16(v[rr*8+4], v[rr*8+5]);
                w4.w = pk_bf16(v[rr*8+6], v[rr*8+7]);
                *(uintx4*)&L_scr[cL][khL * 16 + rr * 8] = w4;
            }
        }
        // x -> regs for sin staging: x[m0+r0s][i0 + kqs*4 .. +3]
        float xs[4];
        {
            float4 xv = *(const float4*)(x + (size_t)(m0 + r0s) * I + i0 + kqs * 4);
            xs[0] = xv.x; xs[1] = xv.y; xs[2] = xv.z; xs[3] = xv.w;
        }
        __syncthreads();   // chunk 0 visible
        short8 lf[2][4];
        if (ngw < 2) {
            #pragma unroll
            for (int kk = 0; kk < 2; ++kk)
                #pragma unroll
                for (int nt = 0; nt < 4; ++nt)
                    lf[kk][nt] = *(const short8*)&L_scr[ngw*64 + nt*16 + l15][kk*32 + quad*8];
        }
        __syncthreads();   // chunk-0 reads done
        // ---- lambda chunk 1 (cols n0+128..n0+255) -> L_scr ----
        {
            const float* lp = lamb + (size_t)(i0 + khL * 16) * O + n0 + 128 + cL;
            float v[16];
            #pragma unroll
            for (int k = 0; k < 16; ++k) v[k] = lp[(size_t)k * O];
            #pragma unroll
            for (int rr = 0; rr < 2; ++rr) {
                uintx4 w4;
                w4.x = pk_bf16(v[rr*8+0], v[rr*8+1]);
                w4.y = pk_bf16(v[rr*8+2], v[rr*8+3]);
                w4.z = pk_bf16(v[rr*8+4], v[rr*8+5]);
                w4.w = pk_bf16(v[rr*8+6], v[rr*8+7]);
                *(uintx4*)&L_scr[cL][khL * 16 + rr * 8] = w4;
            }
        }
        // sins for f=0,1 -> A_sh[0] (both buffers idle at i-tile start)
        *(uintx2*)&A_sh[0][0][r0s][kqs * 4] = sin_pack4(xs, wrev_sh[0], prev_sh[0]);
        *(uintx2*)&A_sh[0][1][r0s][kqs * 4] = sin_pack4(xs, wrev_sh[1], prev_sh[1]);
        __syncthreads();   // chunk 1 + A_sh[0] visible
        if (ngw >= 2) {
            #pragma unroll
            for (int kk = 0; kk < 2; ++kk)
                #pragma unroll
                for (int nt = 0; nt < 4; ++nt)
                    lf[kk][nt] = *(const short8*)&L_scr[(ngw-2)*64 + nt*16 + l15][kk*32 + quad*8];
        }

        // beta prefetch for f=0,1 (global, L2-resident)
        float bA[4], bB[4];
        #pragma unroll
        for (int nt = 0; nt < 4; ++nt) {
            bA[nt] = bp[0 * O + nt * 16];
            bB[nt] = bp[1 * O + nt * 16];
        }
        float rA = r_sh[0], rB = r_sh[1];

        // ---- f-loop: 2 f per iteration, dbuf A_sh, ONE barrier per pair ----
        int cur = 0;
        #pragma unroll 1
        for (int f = 0; f < F; f += 2) {
            const int arow = mg * 16 + l15;
            short8 afA0 = *(const short8*)&A_sh[cur][0][arow][quad * 8];
            short8 afA1 = *(const short8*)&A_sh[cur][0][arow][32 + quad * 8];
            short8 afB0 = *(const short8*)&A_sh[cur][1][arow][quad * 8];
            short8 afB1 = *(const short8*)&A_sh[cur][1][arow][32 + quad * 8];
            float brA[4], brB[4];
            #pragma unroll
            for (int q = 0; q < 4; ++q) { brA[q] = bA[q] * rA; brB[q] = bB[q] * rB; }
            const bool more = (f + 2 < F);
            if (more) {
                // prefetch beta f+2,f+3 into the now-dead bA/bB (hidden under MFMA)
                #pragma unroll
                for (int nt = 0; nt < 4; ++nt) {
                    bA[nt] = bp[(f + 2) * O + nt * 16];
                    bB[nt] = bp[(f + 3) * O + nt * 16];
                }
                rA = r_sh[f + 2]; rB = r_sh[f + 3];
                // sins for f+2 -> other buffer, dovetailed before MFMA chain A
                *(uintx2*)&A_sh[cur ^ 1][0][r0s][kqs * 4] =
                    sin_pack4(xs, wrev_sh[f + 2], prev_sh[f + 2]);
            }
            // MFMA chain A
            #pragma unroll
            for (int nt = 0; nt < 4; ++nt) {
                floatx4 s = __builtin_amdgcn_mfma_f32_16x16x32_bf16(
                    afA0, lf[0][nt], zero4, 0, 0, 0);
                s = __builtin_amdgcn_mfma_f32_16x16x32_bf16(
                    afA1, lf[1][nt], s, 0, 0, 0);
                oacc[nt] += brA[nt] * s;
            }
            if (more) {
                // sins for f+3, dovetailed before MFMA chain B
                *(uintx2*)&A_sh[cur ^ 1][1][r0s][kqs * 4] =
                    sin_pack4(xs, wrev_sh[f + 3], prev_sh[f + 3]);
            }
            // MFMA chain B
            #pragma unroll
            for (int nt = 0; nt < 4; ++nt) {
                floatx4 s = __builtin_amdgcn_mfma_f32_16x16x32_bf16(
                    afB0, lf[0][nt], zero4, 0, 0, 0);
                s = __builtin_amdgcn_mfma_f32_16x16x32_bf16(
                    afB1, lf[1][nt], s, 0, 0, 0);
                oacc[nt] += brB[nt] * s;
            }
            __syncthreads();
            cur ^= 1;
        }
    }

    // ---- epilogue: add per-column constant, store fp32 ----
    #pragma unroll
    for (int nt = 0; nt < 4; ++nt) {
        int cn = ngw * 64 + nt * 16 + l15;
        int gn = n0 + cn;
        float cv = c_sh[cn];
        int gm = m0 + mg * 16 + quad * 4;
        #pragma unroll
        for (int rg = 0; rg < 4; ++rg) {
            out[(size_t)(gm + rg) * O + gn] = oacc[nt][rg] + cv;
        }
    }
}

extern "C" void kernel_launch(void* const* d_in, const int* in_sizes, int n_in,
                              void* d_out, int out_size, void* d_ws, size_t ws_size,
                              hipStream_t stream) {
    const float* x      = (const float*)d_in[0];
    const float* freqs  = (const float*)d_in[1];
    const float* phases = (const float*)d_in[2];
    const float* beta   = (const float*)d_in[3];
    const float* lamb   = (const float*)d_in[4];
    const float* bias   = (const float*)d_in[5];
    float* out = (float*)d_out;

    dim3 grid(512);   // (8192/32) m-blocks * (512/256) n-blocks
    dim3 block(TB);
    hipLaunchKernelGGL(actlayer_kernel, grid, block, 0, stream,
                       x, freqs, phases, beta, lamb, bias, out);
}

// Round 13
// 382.324 us; speedup vs baseline: 1.0959x; 1.0729x over previous
//
#include <hip/hip_runtime.h>
#include <hip/hip_bf16.h>

// ActLayer: out[b,o] = sum_{i,f} norm(sin(w_f x[b,i] + p_f)) * beta[f,o] * lamb[i,o] + bias[o]
//
// Round-15: R14 (390us, 40% occupancy, 89% combined pipe busy) with VALU-work
// removal only (the pipes are saturated; latency-hiding is exhausted):
//   1. Direct v_sin: V_SIN_F32 takes revolutions with internal reduction over
//      +-256 rev; our args are +-3.2 rev. Drop rndne+sub (16 instr/f-pair).
//   2. betaR = beta*r precomputed once into d_ws (128KB) by a micro-kernel;
//      main loop loads betaR directly (drops 8 v_mul/pair + r_sh coupling).
//      Template fallback multiplies in-kernel if ws unavailable.
// Geometry/cadence verbatim R14: BM=32 x BN=256, TB=512 (8 waves, 2m x 4n,
// 16x64/wave), grid 512, A_sh[2] dbuf sin-sharing, 1 barrier per f-pair,
// L_scr two-chunk lambda staging, v_perm bf16 pack, epilogue mapping.

#define TB 512

typedef __attribute__((ext_vector_type(8))) short short8;
typedef __attribute__((ext_vector_type(4))) float floatx4;
typedef __attribute__((ext_vector_type(2))) unsigned int uintx2;
typedef __attribute__((ext_vector_type(4))) unsigned int uintx4;

// pack two fp32 -> two bf16 (round-half-up): two v_add + one v_perm_b32.
__device__ __forceinline__ unsigned pk_bf16(float a, float b) {
    union { float f; unsigned u; } ca, cb;
    ca.f = a; cb.f = b;
    unsigned ua = ca.u + 0x8000u;
    unsigned ub = cb.u + 0x8000u;
    return __builtin_amdgcn_perm(ub, ua, 0x07060302u);
}

// 4 bf16 sin values as 8B packed: sin(2*pi*(x*wfr + pfr)).
// Direct v_sin: args bounded by ~+-3.2 revolutions, well inside HW domain.
__device__ __forceinline__ uintx2 sin_pack4(const float xv[4], float wfr, float pfr) {
    float s[4];
    #pragma unroll
    for (int j = 0; j < 4; ++j) {
        s[j] = __builtin_amdgcn_sinf(fmaf(xv[j], wfr, pfr));
    }
    uintx2 r;
    r.x = pk_bf16(s[0], s[1]);
    r.y = pk_bf16(s[2], s[3]);
    return r;
}

// ---- micro-kernel: betaR[f*O+n] = beta[f*O+n] * r_f  (F*O = 32768 floats) ----
__global__ __launch_bounds__(256)
void betar_kernel(const float* __restrict__ freqs, const float* __restrict__ phases,
                  const float* __restrict__ beta, float* __restrict__ betaR)
{
    int idx = blockIdx.x * 256 + threadIdx.x;   // 0..32767
    int f = idx >> 9;
    float wq = freqs[f], ph = phases[f];
    float e1 = expf(-0.5f * wq * wq);
    float mean = e1 * sinf(ph);
    float e2 = expf(-2.0f * wq * wq);
    float var = 0.5f - 0.5f * e2 * cosf(2.0f * ph) - mean * mean;
    float r = 1.0f / sqrtf(1e-3f + var);
    betaR[idx] = beta[idx] * r;
}

template<bool PRE>
__global__ __launch_bounds__(TB, 4)
void actlayer_kernel(const float* __restrict__ x,
                     const float* __restrict__ freqs,
                     const float* __restrict__ phases,
                     const float* __restrict__ beta,
                     const float* __restrict__ lamb,
                     const float* __restrict__ bias,
                     const float* __restrict__ betaRg,   // ws betaR (PRE) or null
                     float* __restrict__ out)
{
    constexpr int I = 512, F = 64, O = 512;
    const int t  = threadIdx.x;
    const int bx = blockIdx.x;
    const int bn = bx & 1;            // 0..1
    const int bm = bx >> 1;           // 0..255
    const int n0 = bn * 256;
    const int m0 = bm * 32;

    __shared__ __align__(16) unsigned short A_sh[2][2][32][72]; // sin tiles, dbuf, 18432B
    __shared__ __align__(16) unsigned short L_scr[128][72];     // lambda chunk, 18432B
    __shared__ float wrev_sh[F], prev_sh[F], r_sh[F], m_sh[F];
    __shared__ float c_sh[256];

    // ---- prologue: per-f normalization constants ----
    if (t < F) {
        float wq = freqs[t];
        float ph = phases[t];
        float e1 = expf(-0.5f * wq * wq);
        float mean = e1 * sinf(ph);
        float e2 = expf(-2.0f * wq * wq);
        float var = 0.5f - 0.5f * e2 * cosf(2.0f * ph) - mean * mean;
        float r = 1.0f / sqrtf(1e-3f + var);
        wrev_sh[t] = wq * 0.15915494309189535f;
        prev_sh[t] = ph * 0.15915494309189535f;
        r_sh[t] = r;
        m_sh[t] = mean;
    }
    __syncthreads();
    // c_sh[n] = bias - (sum_f betaR*mean) * (sum_i lamb[i][n]); col n0+t (t<256)
    if (t < 256) {
        int col = n0 + t;
        float sb = 0.f;
        #pragma unroll 8
        for (int f = 0; f < F; ++f) {
            float br = PRE ? betaRg[f * O + col] : beta[f * O + col] * r_sh[f];
            sb += br * m_sh[f];
        }
        float sl = 0.f;
        #pragma unroll 8
        for (int i = 0; i < I; ++i) sl += lamb[(size_t)i * O + col];
        c_sh[t] = bias[col] - sb * sl;
    }

    // ---- wave geometry: 8 waves = 2 m-groups x 4 n-groups; tile 16 x 64 ----
    const int lane = t & 63;
    const int wid  = t >> 6;
    const int mg   = wid >> 2;        // 0..1
    const int ngw  = wid & 3;         // 0..3 (cols n0 + ngw*64 .. +63)
    const int l15  = lane & 15;
    const int quad = lane >> 4;
    // staging maps
    const int r0s = t >> 4;           // A staging row 0..31
    const int kqs = t & 15;           // A staging k-quad (k = kqs*4..+3)
    const int cL  = t & 127;          // L staging col within chunk
    const int khL = t >> 7;           // L staging k-quarter 0..3 (16 k each)

    floatx4 oacc[4];
    #pragma unroll
    for (int nt = 0; nt < 4; ++nt) oacc[nt] = (floatx4){0.f, 0.f, 0.f, 0.f};
    const floatx4 zero4 = (floatx4){0.f, 0.f, 0.f, 0.f};

    const float* bp = (PRE ? betaRg : beta) + n0 + ngw * 64 + l15;

    #pragma unroll 1
    for (int it = 0; it < 8; ++it) {
        const int i0 = it * 64;
        // ---- lambda chunk 0 (cols n0..n0+127) -> L_scr ----
        {
            const float* lp = lamb + (size_t)(i0 + khL * 16) * O + n0 + cL;
            float v[16];
            #pragma unroll
            for (int k = 0; k < 16; ++k) v[k] = lp[(size_t)k * O];
            #pragma unroll
            for (int rr = 0; rr < 2; ++rr) {
                uintx4 w4;
                w4.x = pk_bf16(v[rr*8+0], v[rr*8+1]);
                w4.y = pk_bf16(v[rr*8+2], v[rr*8+3]);
                w4.z = pk_bf16(v[rr*8+4], v[rr*8+5]);
                w4.w = pk_bf16(v[rr*8+6], v[rr*8+7]);
                *(uintx4*)&L_scr[cL][khL * 16 + rr * 8] = w4;
            }
        }
        // x -> regs for sin staging: x[m0+r0s][i0 + kqs*4 .. +3]
        float xs[4];
        {
            float4 xv = *(const float4*)(x + (size_t)(m0 + r0s) * I + i0 + kqs * 4);
            xs[0] = xv.x; xs[1] = xv.y; xs[2] = xv.z; xs[3] = xv.w;
        }
        __syncthreads();   // chunk 0 visible
        short8 lf[2][4];
        if (ngw < 2) {
            #pragma unroll
            for (int kk = 0; kk < 2; ++kk)
                #pragma unroll
                for (int nt = 0; nt < 4; ++nt)
                    lf[kk][nt] = *(const short8*)&L_scr[ngw*64 + nt*16 + l15][kk*32 + quad*8];
        }
        __syncthreads();   // chunk-0 reads done
        // ---- lambda chunk 1 (cols n0+128..n0+255) -> L_scr ----
        {
            const float* lp = lamb + (size_t)(i0 + khL * 16) * O + n0 + 128 + cL;
            float v[16];
            #pragma unroll
            for (int k = 0; k < 16; ++k) v[k] = lp[(size_t)k * O];
            #pragma unroll
            for (int rr = 0; rr < 2; ++rr) {
                uintx4 w4;
                w4.x = pk_bf16(v[rr*8+0], v[rr*8+1]);
                w4.y = pk_bf16(v[rr*8+2], v[rr*8+3]);
                w4.z = pk_bf16(v[rr*8+4], v[rr*8+5]);
                w4.w = pk_bf16(v[rr*8+6], v[rr*8+7]);
                *(uintx4*)&L_scr[cL][khL * 16 + rr * 8] = w4;
            }
        }
        // sins for f=0,1 -> A_sh[0] (both buffers idle at i-tile start)
        *(uintx2*)&A_sh[0][0][r0s][kqs * 4] = sin_pack4(xs, wrev_sh[0], prev_sh[0]);
        *(uintx2*)&A_sh[0][1][r0s][kqs * 4] = sin_pack4(xs, wrev_sh[1], prev_sh[1]);
        __syncthreads();   // chunk 1 + A_sh[0] visible
        if (ngw >= 2) {
            #pragma unroll
            for (int kk = 0; kk < 2; ++kk)
                #pragma unroll
                for (int nt = 0; nt < 4; ++nt)
                    lf[kk][nt] = *(const short8*)&L_scr[(ngw-2)*64 + nt*16 + l15][kk*32 + quad*8];
        }

        // betaR prefetch for f=0,1
        float bA[4], bB[4];
        #pragma unroll
        for (int nt = 0; nt < 4; ++nt) {
            bA[nt] = bp[0 * O + nt * 16];
            bB[nt] = bp[1 * O + nt * 16];
        }
        float rA = r_sh[0], rB = r_sh[1];

        // ---- f-loop: 2 f per iteration, dbuf A_sh, ONE barrier per pair ----
        int cur = 0;
        #pragma unroll 1
        for (int f = 0; f < F; f += 2) {
            const int arow = mg * 16 + l15;
            short8 afA0 = *(const short8*)&A_sh[cur][0][arow][quad * 8];
            short8 afA1 = *(const short8*)&A_sh[cur][0][arow][32 + quad * 8];
            short8 afB0 = *(const short8*)&A_sh[cur][1][arow][quad * 8];
            short8 afB1 = *(const short8*)&A_sh[cur][1][arow][32 + quad * 8];
            float brA[4], brB[4];
            #pragma unroll
            for (int q = 0; q < 4; ++q) {
                brA[q] = PRE ? bA[q] : bA[q] * rA;
                brB[q] = PRE ? bB[q] : bB[q] * rB;
            }
            const bool more = (f + 2 < F);
            if (more) {
                #pragma unroll
                for (int nt = 0; nt < 4; ++nt) {
                    bA[nt] = bp[(f + 2) * O + nt * 16];
                    bB[nt] = bp[(f + 3) * O + nt * 16];
                }
                if (!PRE) { rA = r_sh[f + 2]; rB = r_sh[f + 3]; }
                // sins for f+2 -> other buffer, dovetailed before MFMA chain A
                *(uintx2*)&A_sh[cur ^ 1][0][r0s][kqs * 4] =
                    sin_pack4(xs, wrev_sh[f + 2], prev_sh[f + 2]);
            }
            // MFMA chain A
            #pragma unroll
            for (int nt = 0; nt < 4; ++nt) {
                floatx4 s = __builtin_amdgcn_mfma_f32_16x16x32_bf16(
                    afA0, lf[0][nt], zero4, 0, 0, 0);
                s = __builtin_amdgcn_mfma_f32_16x16x32_bf16(
                    afA1, lf[1][nt], s, 0, 0, 0);
                oacc[nt] += brA[nt] * s;
            }
            if (more) {
                // sins for f+3, dovetailed before MFMA chain B
                *(uintx2*)&A_sh[cur ^ 1][1][r0s][kqs * 4] =
                    sin_pack4(xs, wrev_sh[f + 3], prev_sh[f + 3]);
            }
            // MFMA chain B
            #pragma unroll
            for (int nt = 0; nt < 4; ++nt) {
                floatx4 s = __builtin_amdgcn_mfma_f32_16x16x32_bf16(
                    afB0, lf[0][nt], zero4, 0, 0, 0);
                s = __builtin_amdgcn_mfma_f32_16x16x32_bf16(
                    afB1, lf[1][nt], s, 0, 0, 0);
                oacc[nt] += brB[nt] * s;
            }
            __syncthreads();
            cur ^= 1;
        }
    }

    // ---- epilogue: add per-column constant, store fp32 ----
    #pragma unroll
    for (int nt = 0; nt < 4; ++nt) {
        int cn = ngw * 64 + nt * 16 + l15;
        int gn = n0 + cn;
        float cv = c_sh[cn];
        int gm = m0 + mg * 16 + quad * 4;
        #pragma unroll
        for (int rg = 0; rg < 4; ++rg) {
            out[(size_t)(gm + rg) * O + gn] = oacc[nt][rg] + cv;
        }
    }
}

extern "C" void kernel_launch(void* const* d_in, const int* in_sizes, int n_in,
                              void* d_out, int out_size, void* d_ws, size_t ws_size,
                              hipStream_t stream) {
    const float* x      = (const float*)d_in[0];
    const float* freqs  = (const float*)d_in[1];
    const float* phases = (const float*)d_in[2];
    const float* beta   = (const float*)d_in[3];
    const float* lamb   = (const float*)d_in[4];
    const float* bias   = (const float*)d_in[5];
    float* out = (float*)d_out;

    const size_t need = 64 * 512 * sizeof(float);   // 128 KB betaR
    dim3 grid(512);
    dim3 block(TB);
    if (d_ws != nullptr && ws_size >= need) {
        float* betaR = (float*)d_ws;
        hipLaunchKernelGGL(betar_kernel, dim3(128), dim3(256), 0, stream,
                           freqs, phases, beta, betaR);
        hipLaunchKernelGGL(actlayer_kernel<true>, grid, block, 0, stream,
                           x, freqs, phases, beta, lamb, bias, betaR, out);
    } else {
        hipLaunchKernelGGL(actlayer_kernel<false>, grid, block, 0, stream,
                           x, freqs, phases, beta, lamb, bias, nullptr, out);
    }
}